// Round 11
// baseline (150.934 us; speedup 1.0000x reference)
//
#include <hip/hip_runtime.h>
#include <hip/hip_fp16.h>

#define EPSF 1e-6f

typedef _Float16 f16x8 __attribute__((ext_vector_type(8)));
typedef float f32x4 __attribute__((ext_vector_type(4)));

#define BK 64                  // K-tile (halves); LDS A row = 128 B (8 x 16B segs)
#define SMEM_BYTES 75776       // 8 fg regions x 37x64 f32 (3 x 20480 A staging aliases front)
#define BUF_BYTES 20480        // A staging: 160 rows x 128 B

#define AS1 __attribute__((address_space(1)))
#define AS3 __attribute__((address_space(3)))

#define VM_WAIT(N) asm volatile("s_waitcnt vmcnt(" #N ")" ::: "memory")
#define LGKM0()    asm volatile("s_waitcnt lgkmcnt(0)" ::: "memory")

// ---------- wave sum -> scalar (SGPR), fused-DPP version ----------
__device__ __forceinline__ float wave_sum_fast(float x) {
    asm volatile(
        "s_nop 1\n\t"
        "v_add_f32 %0, %0, %0 quad_perm:[1,0,3,2] row_mask:0xf bank_mask:0xf bound_ctrl:0\n\t"
        "s_nop 1\n\t"
        "v_add_f32 %0, %0, %0 quad_perm:[2,3,0,1] row_mask:0xf bank_mask:0xf bound_ctrl:0\n\t"
        "s_nop 1\n\t"
        "v_add_f32 %0, %0, %0 row_half_mirror row_mask:0xf bank_mask:0xf bound_ctrl:0\n\t"
        "s_nop 1\n\t"
        "v_add_f32 %0, %0, %0 row_mirror row_mask:0xf bank_mask:0xf bound_ctrl:0\n\t"
        "s_nop 1\n\t"
        "v_add_f32 %0, %0, %0 row_bcast:15 row_mask:0xf bank_mask:0xf bound_ctrl:0\n\t"
        "s_nop 1\n\t"
        "v_add_f32 %0, %0, %0 row_bcast:31 row_mask:0xf bank_mask:0xf bound_ctrl:0"
        : "+v"(x));
    return __int_as_float(__builtin_amdgcn_readlane(__float_as_int(x), 63));
}

// ---------------- Phase 1: prepend cls, +EPS, L2-normalize, store fp16 ----------------
// A: row-major [64 groups][80 rows][1024]; rows 0..36 = img 2g, 37..73 = img 2g+1.
// B: FRAGMENT-MAJOR by K-32 subtile: Bh[((t*32 + k32)*4 + n)*512 + lane*8].
__global__ __launch_bounds__(256) void norm_kernel(
        const float* __restrict__ img_cls, const float* __restrict__ imgs,
        const float* __restrict__ cap_cls, const float* __restrict__ caps,
        __half* __restrict__ Ah, __half* __restrict__ Bh) {
    __shared__ float red[4];
    const int row = blockIdx.x;
    const int tid = threadIdx.x;

    const float* src = nullptr;
    __half* dsth;
    float eps_add = EPSF;
    if (row < 64 * 80) {
        const int g = row / 80, r = row % 80;
        dsth = Ah + (size_t)row * 1024 + tid * 4;
        int i = -1, rr = 0;
        if (r < 37)      { i = 2 * g;     rr = r; }
        else if (r < 74) { i = 2 * g + 1; rr = r - 37; }
        if (i >= 0) {
            if (rr == 0) { src = img_cls + (size_t)i * 1024; eps_add = 0.0f; }
            else         { src = imgs + ((size_t)i * 36 + (rr - 1)) * 1024; }
        }
    } else {
        const int row2 = row - 64 * 80;
        const int t = row2 >> 6, r = row2 & 63;
        const int n = r >> 4, fr = r & 15;
        const int kt = tid >> 3, q4 = (tid >> 1) & 3, j = (tid & 1) * 4;
        dsth = Bh + ((size_t)(t * 32 + kt) * 4 + n) * 512 + (q4 * 16 + fr) * 8 + j;
        if (r == 0)       { src = cap_cls + (size_t)t * 1024; eps_add = 0.0f; }
        else if (r <= 50) { src = caps + ((size_t)t * 50 + (r - 1)) * 1024; }
    }

    if (src == nullptr) {  // pad row: zeros (uniform across block)
        ushort4 z; z.x = z.y = z.z = z.w = 0;
        *reinterpret_cast<ushort4*>(dsth) = z;
        return;
    }

    float4 v = reinterpret_cast<const float4*>(src)[tid];
    v.x += eps_add; v.y += eps_add; v.z += eps_add; v.w += eps_add;
    float ss = v.x * v.x + v.y * v.y + v.z * v.z + v.w * v.w;
    #pragma unroll
    for (int m = 1; m <= 32; m <<= 1) ss += __shfl_xor(ss, m);
    if ((tid & 63) == 0) red[tid >> 6] = ss;
    __syncthreads();
    const float tot = red[0] + red[1] + red[2] + red[3];
    const float rn = 1.0f / sqrtf(tot);

    ushort4 o;
    o.x = __half_as_ushort(__float2half(v.x * rn));
    o.y = __half_as_ushort(__float2half(v.y * rn));
    o.z = __half_as_ushort(__float2half(v.z * rn));
    o.w = __half_as_ushort(__float2half(v.w * rn));
    *reinterpret_cast<ushort4*>(dsth) = o;
}

// ---------------- Phase 2: fused GEMM (BK=64, 16 tiles) + Sinkhorn, 8 waves ----------------
// Block 160x128, 512 threads / 8 waves; wave (wm2, wn2) computes 80x32.
// A in LDS: THREE 20,480-B buffers (128-B rows), staged 2 tiles ahead via
// global_load_lds; swizzle slot = seg ^ (row&7) (source-permuted, LDS linear)
// -> ds_read_b128 spreads 64 lanes uniformly over all 32 banks.
// B direct global->VGPR (fragment-major), 4 frags/tile, double-buffered
// 2 tiles ahead.  ONE barrier per tile, 16 tiles: stage at kt+1 overwrites
// the buffer read at kt (reads retired via kt's lgkm0 + barrier).
// Octets (8-row x 1KB gloads): 20/tile; waves get o = w, w+8 (+ w+16 if w<4)
// -> a = 3 (w<4) / 2 (w>=4).  Steady vmcnt leaves B(kt+1)·4 + A(kt+1)·a.
__device__ __forceinline__ void stage_octA(const __half* __restrict__ Ag,
                                           __half* buf, int kb, int o, size_t lofs) {
    const __half* src = Ag + (size_t)o * 8192 + kb + lofs;   // 8 rows x 1024 halves
    __builtin_amdgcn_global_load_lds((const AS1 void*)src,
                                     (AS3 void*)(buf + o * 512), 16, 0, 0);
}

__device__ __forceinline__ void stage_A(const __half* __restrict__ Ag,
                                        __half* buf, int kb, int wave, size_t lofs) {
    stage_octA(Ag, buf, kb, wave, lofs);
    stage_octA(Ag, buf, kb, wave + 8, lofs);
    if (wave < 4) stage_octA(Ag, buf, kb, wave + 16, lofs);
}

template <int KS>
__device__ __forceinline__ void ds_af(const __half* buf, int wm2, int fr, int q4,
                                      f16x8 af[5]) {
    const int soff = (((KS * 4 + q4) ^ (fr & 7)) * 8);   // swizzled seg, halves
    #pragma unroll
    for (int m = 0; m < 5; ++m) {
        const int R = wm2 * 80 + m * 16 + fr;
        af[m] = *reinterpret_cast<const f16x8*>(buf + R * BK + soff);
    }
}

__device__ __forceinline__ void load_bf(const __half* __restrict__ Bgw, int kt,
                                        f16x8 bf[4]) {
    const __half* p = Bgw + (size_t)kt * 4096;   // 2 K32-subtiles x 2048 halves
    bf[0] = *reinterpret_cast<const f16x8*>(p);              // ks0, n0
    bf[1] = *reinterpret_cast<const f16x8*>(p + 512);        // ks0, n1
    bf[2] = *reinterpret_cast<const f16x8*>(p + 2048);       // ks1, n0
    bf[3] = *reinterpret_cast<const f16x8*>(p + 2560);       // ks1, n1
}

template <int KS>
__device__ __forceinline__ void mfma_cluster(f32x4 acc[5][2], const f16x8 af[5],
                                             const f16x8 bf[4]) {
    __builtin_amdgcn_s_setprio(1);
    #pragma unroll
    for (int m = 0; m < 5; ++m)
        #pragma unroll
        for (int n = 0; n < 2; ++n)
            acc[m][n] = __builtin_amdgcn_mfma_f32_16x16x32_f16(af[m], bf[KS * 2 + n],
                                                               acc[m][n], 0, 0, 0);
    __builtin_amdgcn_s_setprio(0);
}

__global__ __launch_bounds__(512, 4) void fused_kernel(
        const __half* __restrict__ Ah, const __half* __restrict__ Bh,
        const int* __restrict__ img_lens, const int* __restrict__ cap_lens,
        float* __restrict__ out) {
    __shared__ __align__(16) char smem[SMEM_BYTES];   // 75,776 B -> 2 blocks/CU
    __half* ldsb[3] = { reinterpret_cast<__half*>(smem),
                        reinterpret_cast<__half*>(smem + BUF_BYTES),
                        reinterpret_cast<__half*>(smem + 2 * BUF_BYTES) };

    // XCD-chunked mapping: 8 consecutive blocks share bx across 8 by slices.
    const int idx = blockIdx.x;            // 0..2047
    const int xcd = idx & 7;
    const int within = idx >> 3;           // 0..255
    const int bx = within >> 3;            // 0..31  (A double-group)
    const int by = xcd * 8 + (within & 7); // 0..63  (cap pair)

    const int tid = threadIdx.x;
    const int wave = tid >> 6;             // 0..7
    const int lane = tid & 63;
    const int wm2 = wave >> 2;             // M half
    const int wn2 = wave & 3;              // N quarter
    const int fr = lane & 15;
    const int q4 = lane >> 4;

    const __half* Ag = Ah + (size_t)bx * 160 * 1024;
    const __half* Bgw = Bh + (size_t)(2 * by + (wn2 >> 1)) * 65536
                           + (size_t)((wn2 & 1) * 2) * 512 + lane * 8;

    // A staging source: rsub = lane>>3 (row in 8-row gload); stored slot
    // (lane&7) holds global seg (lane&7) ^ (lane>>3).  LDS dest linear.
    const int segsrc = (lane & 7) ^ (lane >> 3);
    const size_t lofs = (size_t)(lane >> 3) * 1024 + (size_t)(segsrc * 8);

    f32x4 acc[5][2];
    #pragma unroll
    for (int m = 0; m < 5; ++m)
        #pragma unroll
        for (int n = 0; n < 2; ++n) {
            f32x4 z = {0.0f, 0.0f, 0.0f, 0.0f};
            acc[m][n] = z;
        }

    f16x8 bfA[4], bfB[4];

    // Prologue.  Queue: [B0·4, A0·a, B1·4, A1·a]; wait leaves 4+a -> B0,A0 done.
    load_bf(Bgw, 0, bfA);
    stage_A(Ag, ldsb[0], 0, wave, lofs);
    load_bf(Bgw, 1, bfB);
    stage_A(Ag, ldsb[1], BK, wave, lofs);
    if (wave < 4) { VM_WAIT(7); } else { VM_WAIT(6); }
    __builtin_amdgcn_s_barrier();

    // Tile kt: ds ks0 -> 10 MFMA -> ds ks1 -> 10 MFMA -> load B(kt+2) ->
    // lgkm0 (own reads retired) -> stage A(kt+2) into buf[(kt+2)%3] (that
    // buffer was read at kt-1; its reads retired at kt-1's lgkm0+barrier) ->
    // vmcnt(4+a) [B(kt+1), A(kt+1) landed] -> barrier.
    #define GEMM_TILE(KT, RD, ST, CUR)                                \
    {                                                                 \
        f16x8 af[5];                                                  \
        ds_af<0>((RD), wm2, fr, q4, af);                              \
        mfma_cluster<0>(acc, af, (CUR));                              \
        ds_af<1>((RD), wm2, fr, q4, af);                              \
        mfma_cluster<1>(acc, af, (CUR));                              \
        load_bf(Bgw, (KT) + 2, (CUR));                                \
        LGKM0();                                                      \
        stage_A(Ag, (ST), ((KT) + 2) * BK, wave, lofs);               \
        if (wave < 4) { VM_WAIT(7); } else { VM_WAIT(6); }            \
        __builtin_amdgcn_s_barrier();                                 \
    }

    #pragma unroll 1
    for (int kt = 0; kt < 12; kt += 6) {
        GEMM_TILE(kt,     ldsb[0], ldsb[2], bfA);
        GEMM_TILE(kt + 1, ldsb[1], ldsb[0], bfB);
        GEMM_TILE(kt + 2, ldsb[2], ldsb[1], bfA);
        GEMM_TILE(kt + 3, ldsb[0], ldsb[2], bfB);
        GEMM_TILE(kt + 4, ldsb[1], ldsb[0], bfA);
        GEMM_TILE(kt + 5, ldsb[2], ldsb[1], bfB);
    }
    GEMM_TILE(12, ldsb[0], ldsb[2], bfA);   // stages A14, loads B14
    GEMM_TILE(13, ldsb[1], ldsb[0], bfB);   // stages A15, loads B15
    #undef GEMM_TILE

    // ---- tile 14 (no staging/loads; A15+B15 in flight) ----
    {
        f16x8 af[5];
        ds_af<0>(ldsb[2], wm2, fr, q4, af);
        mfma_cluster<0>(acc, af, bfA);         // B(14), landed at kt=13's wait
        ds_af<1>(ldsb[2], wm2, fr, q4, af);
        mfma_cluster<1>(acc, af, bfA);
        LGKM0();
        VM_WAIT(0);                            // A15 + B15 landed
        __builtin_amdgcn_s_barrier();          // A15 visible block-wide
    }
    // ---- tile 15 ----
    {
        f16x8 af[5];
        ds_af<0>(ldsb[0], wm2, fr, q4, af);
        mfma_cluster<0>(acc, af, bfB);
        ds_af<1>(ldsb[0], wm2, fr, q4, af);
        mfma_cluster<1>(acc, af, bfB);
    }

    __syncthreads();   // staging buffers become fg scratch (block-shared)

    // ---------------- fg scatter: 8 regions of 37x64 f32 (9,472 B each) ----------------
    // Region rg = ii*2 + tt covers (img 4bx+ii, cap 2by+tt).  Wave (wm2,wn2)
    // writes rows 0..73 of its M-half x its 32 cols.
    // Cols XOR-swizzled: col ^ (((sr>>2)&3)<<4) -> Sinkhorn reads conflict-free.
    float* fgall = reinterpret_cast<float*>(smem);
    const int tt = wn2 >> 1;
    {
        #pragma unroll
        for (int m = 0; m < 5; ++m) {
            #pragma unroll
            for (int q = 0; q < 4; ++q) {
                const int Rl = m * 16 + q4 * 4 + q;     // 0..79 within M-half
                const int s = (Rl >= 37) ? 1 : 0;
                const int sr = Rl - 37 * s;             // scratch row
                const bool valid = (Rl < 74);
                const int rg = (wm2 * 2 + s) * 2 + tt;
                const int sw = ((sr >> 2) & 3) << 4;
                #pragma unroll
                for (int n = 0; n < 2; ++n) {
                    const int sc = (wn2 & 1) * 32 + n * 16 + fr;
                    if (valid)
                        fgall[rg * 2368 + sr * 64 + (sc ^ sw)] = acc[m][n][q];
                }
            }
        }
    }
    __syncthreads();   // all 8 regions complete

    // ---------------- Sinkhorn: one task per wave, chunk-skipped + fused DPP ----------------
    {
        float* fg = fgall + wave * 2368;
        const int i = 4 * bx + (wave >> 1);
        const int t = 2 * by + (wave & 1);
        const int il = img_lens[i] + 1;        // 2..37
        const int cl = cap_lens[t] + 1;        // 2..51
        const bool vcol = lane < cl;

        #define FGR(r_) fg[(r_) * 64 + (lane ^ ((((r_) >> 2) & 3) << 4))]
        #define CEND(c_) ((((c_) * 8 + 8) < 37) ? ((c_) * 8 + 8) : 37)

        float P[37];
        #pragma unroll
        for (int r = 0; r < 37; ++r) P[r] = 0.0f;

        float ts[4] = {0.f, 0.f, 0.f, 0.f};
        #pragma unroll
        for (int c = 0; c < 5; ++c) {
            if (c * 8 < il) {                       // wave-uniform chunk skip
                #pragma unroll
                for (int r = c * 8; r < CEND(c); ++r) {
                    const float f = FGR(r);
                    const bool act = (r < il) && vcol;
                    const float pe = act ? __expf((f - 1.0f) * 10.0f) : 0.0f;
                    P[r] = pe;
                    ts[r & 3] += pe;
                }
            }
        }
        float tot = (ts[0] + ts[1]) + (ts[2] + ts[3]);
        tot = wave_sum_fast(tot);
        const float s0 = __builtin_amdgcn_rcpf(tot + EPSF);
        #pragma unroll
        for (int c = 0; c < 5; ++c) {
            if (c * 8 < il) {
                #pragma unroll
                for (int r = c * 8; r < CEND(c); ++r) P[r] *= s0;
            }
        }

        const float rmarg = 1.0f / (float)il;
        const float cmarg = 1.0f / (float)cl;
        float csave = 0.0f;
        for (int it = 0; it < 3; ++it) {
            #pragma unroll
            for (int c = 0; c < 5; ++c) {
                if (c * 8 < il) {
                    #pragma unroll
                    for (int r = c * 8; r < CEND(c); ++r) {   // 8 indep chains
                        const float u = wave_sum_fast(P[r]);
                        P[r] *= rmarg * __builtin_amdgcn_rcpf(u + EPSF);
                    }
                }
            }
            float vs[4] = {EPSF, 0.f, 0.f, 0.f};
            #pragma unroll
            for (int c = 0; c < 5; ++c) {
                if (c * 8 < il) {
                    #pragma unroll
                    for (int r = c * 8; r < CEND(c); ++r) vs[r & 3] += P[r];
                }
            }
            const float v = (vs[0] + vs[1]) + (vs[2] + vs[3]);
            const float cs = vcol ? cmarg * __builtin_amdgcn_rcpf(v) : 0.0f;
            if (it < 2) {
                #pragma unroll
                for (int c = 0; c < 5; ++c) {
                    if (c * 8 < il) {
                        #pragma unroll
                        for (int r = c * 8; r < CEND(c); ++r) P[r] *= cs;
                    }
                }
            } else {
                csave = cs;                               // fold last scale into dot
            }
        }

        float ls[4] = {0.f, 0.f, 0.f, 0.f};
        #pragma unroll
        for (int c = 0; c < 5; ++c) {
            if (c * 8 < il) {
                #pragma unroll
                for (int r = c * 8; r < CEND(c); ++r) {
                    const float f = FGR(r);
                    const float fm = (r < il) ? f : 0.0f;   // mask BEFORE multiply
                    ls[r & 3] = fmaf(fm, P[r], ls[r & 3]);
                }
            }
        }
        float local = csave * ((ls[0] + ls[1]) + (ls[2] + ls[3]));
        local = wave_sum_fast(local);
        if (lane == 0) out[i * 128 + t] = local;
        #undef FGR
        #undef CEND
    }
}

extern "C" void kernel_launch(void* const* d_in, const int* in_sizes, int n_in,
                              void* d_out, int out_size, void* d_ws, size_t ws_size,
                              hipStream_t stream) {
    const float* img_cls  = (const float*)d_in[0];
    const float* imgs     = (const float*)d_in[1];
    const float* cap_cls  = (const float*)d_in[2];
    const float* caps     = (const float*)d_in[3];
    const int*   img_lens = (const int*)d_in[4];
    const int*   cap_lens = (const int*)d_in[5];
    float* out = (float*)d_out;

    __half* Ah = (__half*)d_ws;                          // 64*80*1024 halves = 10.5 MB
    __half* Bh = Ah + (size_t)64 * 80 * 1024;            // 128*64*1024 halves = 16.8 MB

    norm_kernel<<<64 * 80 + 128 * 64, 256, 0, stream>>>(img_cls, imgs, cap_cls, caps, Ah, Bh);
    fused_kernel<<<2048, 512, 0, stream>>>(Ah, Bh, img_lens, cap_lens, out);
}

// Round 12
// 143.744 us; speedup vs baseline: 1.0500x; 1.0500x over previous
//
#include <hip/hip_runtime.h>
#include <hip/hip_fp16.h>

#define EPSF 1e-6f

typedef _Float16 f16x8 __attribute__((ext_vector_type(8)));
typedef float f32x4 __attribute__((ext_vector_type(4)));

#define BK 32                  // K-tile (halves); LDS A row = 64 B (4 x 16B segs)
#define SMEM_BYTES 37888       // 4 fg regions x 37x64 f32 (4 x 5120 A staging aliases front)
#define BUF_BYTES 5120         // A staging: 80 rows x 64 B

#define AS1 __attribute__((address_space(1)))
#define AS3 __attribute__((address_space(3)))

#define VM_WAIT(N) asm volatile("s_waitcnt vmcnt(" #N ")" ::: "memory")
#define LGKM0()    asm volatile("s_waitcnt lgkmcnt(0)" ::: "memory")

// ---------- wave sum -> scalar (SGPR), fused-DPP version ----------
__device__ __forceinline__ float wave_sum_fast(float x) {
    asm volatile(
        "s_nop 1\n\t"
        "v_add_f32 %0, %0, %0 quad_perm:[1,0,3,2] row_mask:0xf bank_mask:0xf bound_ctrl:0\n\t"
        "s_nop 1\n\t"
        "v_add_f32 %0, %0, %0 quad_perm:[2,3,0,1] row_mask:0xf bank_mask:0xf bound_ctrl:0\n\t"
        "s_nop 1\n\t"
        "v_add_f32 %0, %0, %0 row_half_mirror row_mask:0xf bank_mask:0xf bound_ctrl:0\n\t"
        "s_nop 1\n\t"
        "v_add_f32 %0, %0, %0 row_mirror row_mask:0xf bank_mask:0xf bound_ctrl:0\n\t"
        "s_nop 1\n\t"
        "v_add_f32 %0, %0, %0 row_bcast:15 row_mask:0xf bank_mask:0xf bound_ctrl:0\n\t"
        "s_nop 1\n\t"
        "v_add_f32 %0, %0, %0 row_bcast:31 row_mask:0xf bank_mask:0xf bound_ctrl:0"
        : "+v"(x));
    return __int_as_float(__builtin_amdgcn_readlane(__float_as_int(x), 63));
}

// ---------------- Phase 1: prepend cls, +EPS, L2-normalize, store fp16 ----------------
// A: row-major [64 groups][80 rows][1024]; rows 0..36 = img 2g, 37..73 = img 2g+1.
// B: FRAGMENT-MAJOR by K-32 subtile: Bh[((t*32 + k32)*4 + n)*512 + lane*8].
__global__ __launch_bounds__(256) void norm_kernel(
        const float* __restrict__ img_cls, const float* __restrict__ imgs,
        const float* __restrict__ cap_cls, const float* __restrict__ caps,
        __half* __restrict__ Ah, __half* __restrict__ Bh) {
    __shared__ float red[4];
    const int row = blockIdx.x;
    const int tid = threadIdx.x;

    const float* src = nullptr;
    __half* dsth;
    float eps_add = EPSF;
    if (row < 64 * 80) {
        const int g = row / 80, r = row % 80;
        dsth = Ah + (size_t)row * 1024 + tid * 4;
        int i = -1, rr = 0;
        if (r < 37)      { i = 2 * g;     rr = r; }
        else if (r < 74) { i = 2 * g + 1; rr = r - 37; }
        if (i >= 0) {
            if (rr == 0) { src = img_cls + (size_t)i * 1024; eps_add = 0.0f; }
            else         { src = imgs + ((size_t)i * 36 + (rr - 1)) * 1024; }
        }
    } else {
        const int row2 = row - 64 * 80;
        const int t = row2 >> 6, r = row2 & 63;
        const int n = r >> 4, fr = r & 15;
        const int kt = tid >> 3, q4 = (tid >> 1) & 3, j = (tid & 1) * 4;
        dsth = Bh + ((size_t)(t * 32 + kt) * 4 + n) * 512 + (q4 * 16 + fr) * 8 + j;
        if (r == 0)       { src = cap_cls + (size_t)t * 1024; eps_add = 0.0f; }
        else if (r <= 50) { src = caps + ((size_t)t * 50 + (r - 1)) * 1024; }
    }

    if (src == nullptr) {  // pad row: zeros (uniform across block)
        ushort4 z; z.x = z.y = z.z = z.w = 0;
        *reinterpret_cast<ushort4*>(dsth) = z;
        return;
    }

    float4 v = reinterpret_cast<const float4*>(src)[tid];
    v.x += eps_add; v.y += eps_add; v.z += eps_add; v.w += eps_add;
    float ss = v.x * v.x + v.y * v.y + v.z * v.z + v.w * v.w;
    #pragma unroll
    for (int m = 1; m <= 32; m <<= 1) ss += __shfl_xor(ss, m);
    if ((tid & 63) == 0) red[tid >> 6] = ss;
    __syncthreads();
    const float tot = red[0] + red[1] + red[2] + red[3];
    const float rn = 1.0f / sqrtf(tot);

    ushort4 o;
    o.x = __half_as_ushort(__float2half(v.x * rn));
    o.y = __half_as_ushort(__float2half(v.y * rn));
    o.z = __half_as_ushort(__float2half(v.z * rn));
    o.w = __half_as_ushort(__float2half(v.w * rn));
    *reinterpret_cast<ushort4*>(dsth) = o;
}

// ---------------- Phase 2: fused GEMM + Sinkhorn, 4-wave / 80x128 blocks ----------------
// Block tile 80 A rows (1 img pair) x 128 B cols (2 caps), 256 threads.
// Wave w covers cols w*32..w*32+31 (cap tt = w>>1, col half = w&1); each wave
// computes 80x32 -> acc 5x2 = 40 AGPR (same per-wave job as the 8-wave
// version, but 4 blocks/CU = 4 independent barrier/vmcnt domains per CU).
// A in LDS: 4 buffers, staged 3 tiles ahead; conflict-free XOR swizzle.
// B direct global->VGPR (fragment-major), double-buffered 2 tiles ahead.
// One barrier/tile.  5 A-hexadecets/tile: wave w takes o=w; wave 0 also o=4
// -> a = 2 (wave 0) / 1 (waves 1-3).  Steady vmcnt leaves
// [A(kt+2)a, B(kt+2)2, A(kt+3)a] = 2a+2 -> 6 / 4.
__device__ __forceinline__ void stage_octA(const __half* __restrict__ Ag,
                                           __half* buf, int kb, int o, size_t lofs) {
    const __half* src = Ag + (size_t)o * 16384 + kb + lofs;   // 16 rows x 1024 halves
    __builtin_amdgcn_global_load_lds((const AS1 void*)src,
                                     (AS3 void*)(buf + o * 512), 16, 0, 0);
}

__device__ __forceinline__ void stage_A(const __half* __restrict__ Ag,
                                        __half* buf, int kb, int wave, size_t lofs) {
    stage_octA(Ag, buf, kb, wave, lofs);
    if (wave == 0) stage_octA(Ag, buf, kb, 4, lofs);
}

__device__ __forceinline__ void ds_af(const __half* buf, int fr, int q4,
                                      f16x8 af[5]) {
    const int soff = ((q4 ^ ((fr >> 1) & 3)) * 8);   // swizzled seg, halves
    #pragma unroll
    for (int m = 0; m < 5; ++m) {
        const int R = m * 16 + fr;
        af[m] = *reinterpret_cast<const f16x8*>(buf + R * BK + soff);
    }
}

__device__ __forceinline__ void load_bf(const __half* __restrict__ Bgw, int kt,
                                        f16x8 bf[2]) {
    const __half* p = Bgw + (size_t)kt * 2048;   // Bgw has +frag_base+lane*8
    bf[0] = *reinterpret_cast<const f16x8*>(p);
    bf[1] = *reinterpret_cast<const f16x8*>(p + 512);
}

__device__ __forceinline__ void mfma_cluster(f32x4 acc[5][2], const f16x8 af[5],
                                             const f16x8 bf[2]) {
    __builtin_amdgcn_s_setprio(1);
    #pragma unroll
    for (int m = 0; m < 5; ++m)
        #pragma unroll
        for (int n = 0; n < 2; ++n)
            acc[m][n] = __builtin_amdgcn_mfma_f32_16x16x32_f16(af[m], bf[n], acc[m][n], 0, 0, 0);
    __builtin_amdgcn_s_setprio(0);
}

__global__ __launch_bounds__(256, 4) void fused_kernel(
        const __half* __restrict__ Ah, const __half* __restrict__ Bh,
        const int* __restrict__ img_lens, const int* __restrict__ cap_lens,
        float* __restrict__ out) {
    __shared__ __align__(16) char smem[SMEM_BYTES];   // 37,888 B -> 4 blocks/CU
    __half* lds0 = reinterpret_cast<__half*>(smem);
    __half* lds1 = reinterpret_cast<__half*>(smem + BUF_BYTES);
    __half* lds2 = reinterpret_cast<__half*>(smem + 2 * BUF_BYTES);
    __half* lds3 = reinterpret_cast<__half*>(smem + 3 * BUF_BYTES);

    // XCD-chunked mapping: 8 consecutive blocks share bx across 8 by slices.
    const int idx = blockIdx.x;            // 0..4095
    const int xcd = idx & 7;
    const int within = idx >> 3;           // 0..511
    const int bx = within >> 3;            // 0..63  (A group = img pair)
    const int by = xcd * 8 + (within & 7); // 0..63  (cap pair)

    const int tid = threadIdx.x;
    const int wave = tid >> 6;             // 0..3
    const int lane = tid & 63;
    const int fr = lane & 15;
    const int q4 = lane >> 4;

    const __half* Ag = Ah + (size_t)bx * 80 * 1024;
    // wave's cap t = 2by + (wave>>1); frag base = (wave&1)*2 frags
    const __half* Bgw = Bh + (size_t)(2 * by + (wave >> 1)) * 65536
                           + (size_t)((wave & 1) * 2) * 512 + lane * 8;

    // A staging source: rsub = lane>>2 (row in hexadecet); stored slot (lane&3)
    // holds global seg (lane&3) ^ ((lane>>3)&3).  LDS dest linear.
    const int rsub = lane >> 2;
    const int segsrc = (lane & 3) ^ ((lane >> 3) & 3);
    const size_t lofs = (size_t)rsub * 1024 + (size_t)(segsrc * 8);

    f32x4 acc[5][2];
    #pragma unroll
    for (int m = 0; m < 5; ++m)
        #pragma unroll
        for (int n = 0; n < 2; ++n) {
            f32x4 z = {0.0f, 0.0f, 0.0f, 0.0f};
            acc[m][n] = z;
        }

    f16x8 bfA[2], bfB[2];

    // Prologue.  Queue: [B0·2, A0·a, B1·2, A1·a, A2·a]; wait leaves 2+2a.
    load_bf(Bgw, 0, bfA);
    stage_A(Ag, lds0, 0, wave, lofs);
    load_bf(Bgw, 1, bfB);
    stage_A(Ag, lds1, BK, wave, lofs);
    stage_A(Ag, lds2, 2 * BK, wave, lofs);
    if (wave == 0) { VM_WAIT(6); } else { VM_WAIT(4); }
    __builtin_amdgcn_s_barrier();

    // Tile kt: ds af(buf[kt&3]); MFMA; load B(kt+2); lgkm0 (own reads
    // retired); stage A(kt+3) into the buffer read at kt-1 (its reads
    // retired at kt-1's lgkm0 + barrier); vmcnt(2a+2) [A(kt+1), B(kt+1)
    // landed]; barrier.
    #define GEMM_TILE(KT, RDBUF, STBUF, CUR)                          \
    {                                                                 \
        f16x8 af[5];                                                  \
        ds_af((RDBUF), fr, q4, af);                                   \
        mfma_cluster(acc, af, (CUR));                                 \
        load_bf(Bgw, (KT) + 2, (CUR));                                \
        LGKM0();                                                      \
        stage_A(Ag, (STBUF), ((KT) + 3) * BK, wave, lofs);            \
        if (wave == 0) { VM_WAIT(6); } else { VM_WAIT(4); }           \
        __builtin_amdgcn_s_barrier();                                 \
    }

    #pragma unroll 1
    for (int kt = 0; kt < 28; kt += 4) {
        GEMM_TILE(kt,     lds0, lds3, bfA);
        GEMM_TILE(kt + 1, lds1, lds0, bfB);
        GEMM_TILE(kt + 2, lds2, lds1, bfA);
        GEMM_TILE(kt + 3, lds3, lds2, bfB);
    }
    GEMM_TILE(28, lds0, lds3, bfA);   // stages A31, loads B30
    #undef GEMM_TILE

    // ---- tile 29: no staging; load B31 ----
    {
        f16x8 af[5];
        ds_af(lds1, fr, q4, af);
        mfma_cluster(acc, af, bfB);            // B(29)
        load_bf(Bgw, 31, bfB);
        LGKM0();
        // queue: A30·a, B30·2, A31·a, B31·2 ; need A30,B30 -> leave a+2
        if (wave == 0) { VM_WAIT(4); } else { VM_WAIT(3); }
        __builtin_amdgcn_s_barrier();
    }
    // ---- tile 30 ----
    {
        f16x8 af[5];
        ds_af(lds2, fr, q4, af);
        mfma_cluster(acc, af, bfA);            // B(30)
        LGKM0();
        VM_WAIT(2);                            // A31 landed; B31 in flight
        __builtin_amdgcn_s_barrier();
    }
    // ---- tile 31 ----
    {
        f16x8 af[5];
        ds_af(lds3, fr, q4, af);
        VM_WAIT(0);                            // B31 landed
        mfma_cluster(acc, af, bfB);
    }

    __syncthreads();   // staging buffers become fg scratch (block-shared)

    // ---------------- fg scatter: 4 regions of 37x64 f32 (9,472 B each) ----------------
    // Region rg = s*2 + tt covers (img 2bx+s, cap 2by+tt).  Wave w (cap
    // tt = w>>1, col half = w&1) writes rows 0..73 x its 32 cols.
    // Cols XOR-swizzled: col ^ (((sr>>2)&3)<<4) -> Sinkhorn reads conflict-free.
    float* fgall = reinterpret_cast<float*>(smem);
    {
        const int ttw = wave >> 1;
        #pragma unroll
        for (int m = 0; m < 5; ++m) {
            #pragma unroll
            for (int q = 0; q < 4; ++q) {
                const int Rl = m * 16 + q4 * 4 + q;     // 0..79
                const int s = (Rl >= 37) ? 1 : 0;
                const int sr = Rl - 37 * s;             // scratch row
                const bool valid = (Rl < 74);
                const int rg = s * 2 + ttw;
                const int sw = ((sr >> 2) & 3) << 4;
                #pragma unroll
                for (int n = 0; n < 2; ++n) {
                    const int sc = (wave & 1) * 32 + n * 16 + fr;
                    if (valid)
                        fgall[rg * 2368 + sr * 64 + (sc ^ sw)] = acc[m][n][q];
                }
            }
        }
    }
    __syncthreads();   // all 4 regions complete

    // ---------------- Sinkhorn: one task per wave, chunk-skipped + fused DPP ----------------
    // Wave w handles region w: img i = 2bx + (w>>1), cap t = 2by + (w&1).
    {
        float* fg = fgall + wave * 2368;
        const int i = 2 * bx + (wave >> 1);
        const int t = 2 * by + (wave & 1);
        const int il = img_lens[i] + 1;        // 2..37
        const int cl = cap_lens[t] + 1;        // 2..51
        const bool vcol = lane < cl;

        #define FGR(r_) fg[(r_) * 64 + (lane ^ ((((r_) >> 2) & 3) << 4))]
        #define CEND(c_) ((((c_) * 8 + 8) < 37) ? ((c_) * 8 + 8) : 37)

        float P[37];
        #pragma unroll
        for (int r = 0; r < 37; ++r) P[r] = 0.0f;

        float ts[4] = {0.f, 0.f, 0.f, 0.f};
        #pragma unroll
        for (int c = 0; c < 5; ++c) {
            if (c * 8 < il) {                       // wave-uniform chunk skip
                #pragma unroll
                for (int r = c * 8; r < CEND(c); ++r) {
                    const float f = FGR(r);
                    const bool act = (r < il) && vcol;
                    const float pe = act ? __expf((f - 1.0f) * 10.0f) : 0.0f;
                    P[r] = pe;
                    ts[r & 3] += pe;
                }
            }
        }
        float tot = (ts[0] + ts[1]) + (ts[2] + ts[3]);
        tot = wave_sum_fast(tot);
        const float s0 = __builtin_amdgcn_rcpf(tot + EPSF);
        #pragma unroll
        for (int c = 0; c < 5; ++c) {
            if (c * 8 < il) {
                #pragma unroll
                for (int r = c * 8; r < CEND(c); ++r) P[r] *= s0;
            }
        }

        const float rmarg = 1.0f / (float)il;
        const float cmarg = 1.0f / (float)cl;
        float csave = 0.0f;
        for (int it = 0; it < 3; ++it) {
            #pragma unroll
            for (int c = 0; c < 5; ++c) {
                if (c * 8 < il) {
                    #pragma unroll
                    for (int r = c * 8; r < CEND(c); ++r) {   // 8 indep chains
                        const float u = wave_sum_fast(P[r]);
                        P[r] *= rmarg * __builtin_amdgcn_rcpf(u + EPSF);
                    }
                }
            }
            float vs[4] = {EPSF, 0.f, 0.f, 0.f};
            #pragma unroll
            for (int c = 0; c < 5; ++c) {
                if (c * 8 < il) {
                    #pragma unroll
                    for (int r = c * 8; r < CEND(c); ++r) vs[r & 3] += P[r];
                }
            }
            const float v = (vs[0] + vs[1]) + (vs[2] + vs[3]);
            const float cs = vcol ? cmarg * __builtin_amdgcn_rcpf(v) : 0.0f;
            if (it < 2) {
                #pragma unroll
                for (int c = 0; c < 5; ++c) {
                    if (c * 8 < il) {
                        #pragma unroll
                        for (int r = c * 8; r < CEND(c); ++r) P[r] *= cs;
                    }
                }
            } else {
                csave = cs;                               // fold last scale into dot
            }
        }

        float ls[4] = {0.f, 0.f, 0.f, 0.f};
        #pragma unroll
        for (int c = 0; c < 5; ++c) {
            if (c * 8 < il) {
                #pragma unroll
                for (int r = c * 8; r < CEND(c); ++r) {
                    const float f = FGR(r);
                    const float fm = (r < il) ? f : 0.0f;   // mask BEFORE multiply
                    ls[r & 3] = fmaf(fm, P[r], ls[r & 3]);
                }
            }
        }
        float local = csave * ((ls[0] + ls[1]) + (ls[2] + ls[3]));
        local = wave_sum_fast(local);
        if (lane == 0) out[i * 128 + t] = local;
        #undef FGR
        #undef CEND
    }
}

extern "C" void kernel_launch(void* const* d_in, const int* in_sizes, int n_in,
                              void* d_out, int out_size, void* d_ws, size_t ws_size,
                              hipStream_t stream) {
    const float* img_cls  = (const float*)d_in[0];
    const float* imgs     = (const float*)d_in[1];
    const float* cap_cls  = (const float*)d_in[2];
    const float* caps     = (const float*)d_in[3];
    const int*   img_lens = (const int*)d_in[4];
    const int*   cap_lens = (const int*)d_in[5];
    float* out = (float*)d_out;

    __half* Ah = (__half*)d_ws;                          // 64*80*1024 halves = 10.5 MB
    __half* Bh = Ah + (size_t)64 * 80 * 1024;            // 128*64*1024 halves = 16.8 MB

    norm_kernel<<<64 * 80 + 128 * 64, 256, 0, stream>>>(img_cls, imgs, cap_cls, caps, Ah, Bh);
    fused_kernel<<<4096, 256, 0, stream>>>(Ah, Bh, img_lens, cap_lens, out);
}